// Round 10
// baseline (165.771 us; speedup 1.0000x reference)
//
#include <hip/hip_runtime.h>

typedef _Float16 half2v __attribute__((ext_vector_type(2)));
typedef _Float16 half4v __attribute__((ext_vector_type(4)));
typedef _Float16 half8v __attribute__((ext_vector_type(8)));

#define HH 1024
#define OHW 256
#define TH 16
#define TW 64
#define NR 80        // input-tile rows
#define NCH 34       // data chunks (8 halves) per row = 272 cols
#define TCHP 36      // padded chunks per row
#define ROWH (TCHP*8) // 288 halves per row
#define NTHREADS 128
#define NCHUNKS (NR*NCH)   // 2720
#define ESPAN 528
#define ECHUNK (ESPAN/4)

#if defined(__has_builtin)
#  if __has_builtin(__builtin_amdgcn_fdot2)
#    define HAS_FDOT2 1
#  endif
#endif
#ifndef HAS_FDOT2
#  define HAS_FDOT2 0
#endif

__constant__ float DEC12c[12] = {
  -1.20162964e-04f,  1.615524292e-03f, -1.0385513306e-02f,  4.3619155884e-02f,
  -1.45397186478e-01f, 6.10668182370e-01f, 6.10668182370e-01f, -1.45397186478e-01f,
   4.3619155884e-02f, -1.0385513306e-02f,  1.615524292e-03f, -1.20162964e-04f
};

__device__ __forceinline__ int clampi(int v) { return v < 0 ? 0 : (v > HH - 1 ? HH - 1 : v); }

__device__ __forceinline__ int swzc(int c, int r) {
  return c ^ ((c >> 3) & 1) ^ ((r >> 2) & 3);
}

__device__ __forceinline__ half2v mk2(_Float16 a, _Float16 b) {
  half2v r; r.x = a; r.y = b; return r;
}

template<int J>
__device__ __forceinline__ half2v sel(half8v a, half8v b, half8v c, half8v d) {
  constexpr int V = J >> 2, E = J & 3;
  const half8v s = (V == 0) ? a : (V == 1) ? b : (V == 2) ? c : d;
  return mk2(s[2 * E], s[2 * E + 1]);
}
template<int E>
__device__ __forceinline__ half2v g2(half8v v) { return mk2(v[2 * E], v[2 * E + 1]); }

__device__ __forceinline__ float dot2acc(half2v w, half2v k, float acc) {
#if HAS_FDOT2
  return __builtin_amdgcn_fdot2(w, k, acc, false);
#else
  return acc + (float)w.x * (float)k.x + (float)w.y * (float)k.y;
#endif
}

// ---------------- main kernel: row-paired f16 dot2, 5-slot kernel rotation ----------------
__global__ __launch_bounds__(NTHREADS, 3) void dgp_main(
    const float* __restrict__ inp, const float* __restrict__ mtfp,
    const int* __restrict__ rp, const int* __restrict__ cp,
    float* __restrict__ outg) {
  __shared__ __align__(64) _Float16 tile[NR * ROWH];   // 46080 B
  __shared__ __align__(64) half2v ckh[20 * 16];        // row stride 64B (20 taps used)
  __shared__ float kva[180];
  __shared__ float mlds[81];
  __shared__ float avs[12], bvs[12];

  const int tid = threadIdx.x;
  const int bxt = blockIdx.x, by = blockIdx.y, bz = blockIdx.z;
  const int chC = bz & 7;
  const int rv = rp[bz], cv = cp[bz];
  const int ri = rv >> 1, rf = rv & 1, ci = cv >> 1, cf = cv & 1;
  const int Ri0 = 2 + 4 * TH * by - ri;
  const int Cj0 = 2 + 4 * TW * bxt - ci;
  const int R0 = Ri0 - 10, C0 = Cj0 - 10;

  if (tid < 12)       avs[tid] = rf ? DEC12c[tid] : (tid == 6 ? 1.f : 0.f);
  else if (tid < 24)  bvs[tid - 12] = cf ? DEC12c[tid - 12] : (tid - 12 == 6 ? 1.f : 0.f);
  else if (tid < 105) { const int m = tid - 24; mlds[m] = mtfp[m * 8 + chC]; }
  __syncthreads();

  for (int i = tid; i < 180; i += NTHREADS) {
    const int S = i / 9, v = i - S * 9;
    const int plo = (S - 8 > 0) ? S - 8 : 0, phi = (S < 11) ? S : 11;
    float s1 = 0.f;
    for (int p = plo; p <= phi; ++p) s1 += avs[p] * mlds[(S - p) * 9 + v];
    kva[i] = s1;
  }
  __syncthreads();

  for (int i = tid; i < 200; i += NTHREADS) {
    const int S = i / 10, m = i - S * 10;
    float s[2];
    #pragma unroll
    for (int h = 0; h < 2; ++h) {
      const int T = 2 * m + h;
      const int qlo = (T - 8 > 0) ? T - 8 : 0, qhi = (T < 11) ? T : 11;
      float acc = 0.f;
      for (int q = qlo; q <= qhi; ++q) acc += bvs[q] * kva[S * 9 + (T - q)];
      s[h] = acc;
    }
    ckh[S * 16 + m] = mk2((_Float16)s[0], (_Float16)s[1]);
  }

  // ---- staging: interior blocks use batched issue-then-write; border blocks clamp ----
  const float* src = inp + ((size_t)bz << 20);
  const bool interior = (R0 >= 0) && (R0 + NR - 1 < HH) && (C0 >= 0) && (C0 + NCH * 8 - 1 < HH);
  if (interior) {
    for (int i0 = tid; i0 < NCHUNKS; i0 += 4 * NTHREADS) {
      const int i1 = i0 + NTHREADS, i2 = i0 + 2 * NTHREADS, i3 = i0 + 3 * NTHREADS;
      float4 p0a, p0b, p1a, p1b, p2a, p2b, p3a, p3b;
      unsigned rr0, g0, rr1, g1, rr2, g2v, rr3, g3;
      rr0 = (unsigned)i0 / 34u; g0 = (unsigned)i0 - 34u * rr0;
      { const float* a = src + ((R0 + (int)rr0) << 10) + C0 + 8 * (int)g0;
        p0a = *(const float4*)a; p0b = *(const float4*)(a + 4); }
      if (i1 < NCHUNKS) { rr1 = (unsigned)i1 / 34u; g1 = (unsigned)i1 - 34u * rr1;
        const float* a = src + ((R0 + (int)rr1) << 10) + C0 + 8 * (int)g1;
        p1a = *(const float4*)a; p1b = *(const float4*)(a + 4); }
      if (i2 < NCHUNKS) { rr2 = (unsigned)i2 / 34u; g2v = (unsigned)i2 - 34u * rr2;
        const float* a = src + ((R0 + (int)rr2) << 10) + C0 + 8 * (int)g2v;
        p2a = *(const float4*)a; p2b = *(const float4*)(a + 4); }
      if (i3 < NCHUNKS) { rr3 = (unsigned)i3 / 34u; g3 = (unsigned)i3 - 34u * rr3;
        const float* a = src + ((R0 + (int)rr3) << 10) + C0 + 8 * (int)g3;
        p3a = *(const float4*)a; p3b = *(const float4*)(a + 4); }
#define CVW(rr, g, pa, pb) do {                                          \
        _Float16 h[8];                                                   \
        h[0]=(_Float16)pa.x; h[1]=(_Float16)pa.y; h[2]=(_Float16)pa.z;   \
        h[3]=(_Float16)pa.w; h[4]=(_Float16)pb.x; h[5]=(_Float16)pb.y;   \
        h[6]=(_Float16)pb.z; h[7]=(_Float16)pb.w;                        \
        __builtin_memcpy(tile + (int)(rr) * ROWH + (swzc((int)(g), (int)(rr)) << 3), h, 16); \
      } while (0)
      CVW(rr0, g0, p0a, p0b);
      if (i1 < NCHUNKS) CVW(rr1, g1, p1a, p1b);
      if (i2 < NCHUNKS) CVW(rr2, g2v, p2a, p2b);
      if (i3 < NCHUNKS) CVW(rr3, g3, p3a, p3b);
#undef CVW
    }
  } else {
    for (int idx = tid; idx < NCHUNKS; idx += NTHREADS) {
      const unsigned rru = (unsigned)idx / 34u;
      const int rr = (int)rru, g = idx - 34 * rr;
      const float* grow = src + (clampi(R0 + rr) << 10);
      const int c0 = C0 + 8 * g;
      float v[8];
      if (c0 >= 0 && c0 + 7 <= HH - 1) {
        __builtin_memcpy(v, grow + c0, 32);
      } else {
        #pragma unroll
        for (int i = 0; i < 8; ++i) v[i] = grow[clampi(c0 + i)];
      }
      _Float16 h[8];
      #pragma unroll
      for (int i = 0; i < 8; ++i) h[i] = (_Float16)v[i];
      __builtin_memcpy(tile + rr * ROWH + (swzc(g, rr) << 3), h, 16);
    }
  }
  __syncthreads();

  const int ty = tid >> 4;   // 0..7 -> output rows 2ty, 2ty+1
  const int tx = tid & 15;   // 0..15 -> 4 horizontal outputs
  const int rbase = 8 * ty;

  float a0 = 0.f, a1 = 0.f, a2 = 0.f, a3 = 0.f;   // row 2ty
  float b0 = 0.f, b1 = 0.f, b2 = 0.f, b3 = 0.f;   // row 2ty+1
  half8v we0, we1, we2, we3, wo0, wo1, wo2, wo3;
  half8v kA0, kA1, kB0, kB1, kC0, kC1, kD0, kD1, kE0, kE1;
  half4v kA2, kB2, kC2, kD2, kE2;

#define LDW(W0, W1, W2, W3, s) do {                                      \
    const int r_ = rbase + (s);                                          \
    const _Float16* rp_ = tile + r_ * ROWH;                              \
    W0 = *(const half8v*)(rp_ + (swzc(2 * tx + 0, r_) << 3));            \
    W1 = *(const half8v*)(rp_ + (swzc(2 * tx + 1, r_) << 3));            \
    W2 = *(const half8v*)(rp_ + (swzc(2 * tx + 2, r_) << 3));            \
    W3 = *(const half8v*)(rp_ + (swzc(2 * tx + 3, r_) << 3));            \
  } while (0)
#define LDK(K0, K1, K2x, s) do {                                         \
    const _Float16* kp_ = (const _Float16*)(ckh + (s) * 16);             \
    K0 = *(const half8v*)(kp_);                                          \
    K1 = *(const half8v*)(kp_ + 8);                                      \
    K2x = *(const half4v*)(kp_ + 16);                                    \
  } while (0)
#define ROWX(o, W0, W1, W2, W3, K0, K1, K2x, A)                          \
    A = dot2acc(sel<(o) + 0>(W0, W1, W2, W3), g2<0>(K0), A);             \
    A = dot2acc(sel<(o) + 1>(W0, W1, W2, W3), g2<1>(K0), A);             \
    A = dot2acc(sel<(o) + 2>(W0, W1, W2, W3), g2<2>(K0), A);             \
    A = dot2acc(sel<(o) + 3>(W0, W1, W2, W3), g2<3>(K0), A);             \
    A = dot2acc(sel<(o) + 4>(W0, W1, W2, W3), g2<0>(K1), A);             \
    A = dot2acc(sel<(o) + 5>(W0, W1, W2, W3), g2<1>(K1), A);             \
    A = dot2acc(sel<(o) + 6>(W0, W1, W2, W3), g2<2>(K1), A);             \
    A = dot2acc(sel<(o) + 7>(W0, W1, W2, W3), g2<3>(K1), A);             \
    A = dot2acc(sel<(o) + 8>(W0, W1, W2, W3), mk2(K2x[0], K2x[1]), A);   \
    A = dot2acc(sel<(o) + 9>(W0, W1, W2, W3), mk2(K2x[2], K2x[3]), A);
#define DO_A(W0, W1, W2, W3, K0, K1, K2x)                                \
    ROWX(0, W0, W1, W2, W3, K0, K1, K2x, a0)                             \
    ROWX(2, W0, W1, W2, W3, K0, K1, K2x, a1)                             \
    ROWX(4, W0, W1, W2, W3, K0, K1, K2x, a2)                             \
    ROWX(6, W0, W1, W2, W3, K0, K1, K2x, a3)
#define DO_B(W0, W1, W2, W3, K0, K1, K2x)                                \
    ROWX(0, W0, W1, W2, W3, K0, K1, K2x, b0)                             \
    ROWX(2, W0, W1, W2, W3, K0, K1, K2x, b1)                             \
    ROWX(4, W0, W1, W2, W3, K0, K1, K2x, b2)                             \
    ROWX(6, W0, W1, W2, W3, K0, K1, K2x, b3)

  // s = 0..3: out-row A only (kernel row s into rotating slot)
  LDW(we0, we1, we2, we3, 0);  LDK(kA0, kA1, kA2, 0);  DO_A(we0, we1, we2, we3, kA0, kA1, kA2);
  LDW(wo0, wo1, wo2, wo3, 1);  LDK(kB0, kB1, kB2, 1);  DO_A(wo0, wo1, wo2, wo3, kB0, kB1, kB2);
  LDW(we0, we1, we2, we3, 2);  LDK(kC0, kC1, kC2, 2);  DO_A(we0, we1, we2, we3, kC0, kC1, kC2);
  LDW(wo0, wo1, wo2, wo3, 3);  LDK(kD0, kD1, kD2, 3);  DO_A(wo0, wo1, wo2, wo3, kD0, kD1, kD2);
  // s = 4..19: both rows; new slot = s%5, old slot = (s-4)%5
#define STEP_BOTH(s, WN0, WN1, WN2, WN3, NK0, NK1, NK2x, OK0, OK1, OK2x) \
    LDW(WN0, WN1, WN2, WN3, s);  LDK(NK0, NK1, NK2x, s);                 \
    DO_B(WN0, WN1, WN2, WN3, OK0, OK1, OK2x);                            \
    DO_A(WN0, WN1, WN2, WN3, NK0, NK1, NK2x);
  STEP_BOTH(4,  we0, we1, we2, we3, kE0, kE1, kE2, kA0, kA1, kA2)
  STEP_BOTH(5,  wo0, wo1, wo2, wo3, kA0, kA1, kA2, kB0, kB1, kB2)
  STEP_BOTH(6,  we0, we1, we2, we3, kB0, kB1, kB2, kC0, kC1, kC2)
  STEP_BOTH(7,  wo0, wo1, wo2, wo3, kC0, kC1, kC2, kD0, kD1, kD2)
  STEP_BOTH(8,  we0, we1, we2, we3, kD0, kD1, kD2, kE0, kE1, kE2)
  STEP_BOTH(9,  wo0, wo1, wo2, wo3, kE0, kE1, kE2, kA0, kA1, kA2)
  STEP_BOTH(10, we0, we1, we2, we3, kA0, kA1, kA2, kB0, kB1, kB2)
  STEP_BOTH(11, wo0, wo1, wo2, wo3, kB0, kB1, kB2, kC0, kC1, kC2)
  STEP_BOTH(12, we0, we1, we2, we3, kC0, kC1, kC2, kD0, kD1, kD2)
  STEP_BOTH(13, wo0, wo1, wo2, wo3, kD0, kD1, kD2, kE0, kE1, kE2)
  STEP_BOTH(14, we0, we1, we2, we3, kE0, kE1, kE2, kA0, kA1, kA2)
  STEP_BOTH(15, wo0, wo1, wo2, wo3, kA0, kA1, kA2, kB0, kB1, kB2)
  STEP_BOTH(16, we0, we1, we2, we3, kB0, kB1, kB2, kC0, kC1, kC2)
  STEP_BOTH(17, wo0, wo1, wo2, wo3, kC0, kC1, kC2, kD0, kD1, kD2)
  STEP_BOTH(18, we0, we1, we2, we3, kD0, kD1, kD2, kE0, kE1, kE2)
  STEP_BOTH(19, wo0, wo1, wo2, wo3, kE0, kE1, kE2, kA0, kA1, kA2)
  // s = 20..23: out-row B only; old slot = (s-4)%5
  LDW(we0, we1, we2, we3, 20); DO_B(we0, we1, we2, we3, kB0, kB1, kB2);
  LDW(wo0, wo1, wo2, wo3, 21); DO_B(wo0, wo1, wo2, wo3, kC0, kC1, kC2);
  LDW(we0, we1, we2, we3, 22); DO_B(we0, we1, we2, we3, kD0, kD1, kD2);
  LDW(wo0, wo1, wo2, wo3, 23); DO_B(wo0, wo1, wo2, wo3, kE0, kE1, kE2);
#undef LDW
#undef LDK
#undef ROWX
#undef DO_A
#undef DO_B
#undef STEP_BOTH

  const int oiA = TH * by + 2 * ty;
  float* orowA = outg + ((size_t)bz * OHW + oiA) * OHW + TW * bxt + 4 * tx;
  orowA[0] = a0; orowA[1] = a1; orowA[2] = a2; orowA[3] = a3;
  float* orowB = orowA + OHW;
  orowB[0] = b0; orowB[1] = b1; orowB[2] = b2; orowB[3] = b3;
}

// ---------------- edge fixup: masked-separable recompute of rows/cols {0,1,255} ----------------
__global__ __launch_bounds__(128) void dgp_edgefix(
    const float* __restrict__ inp, const float* __restrict__ mtfp,
    const int* __restrict__ rp, const int* __restrict__ cp,
    float* __restrict__ outg) {
  __shared__ __align__(16) float tile[20 * ESPAN];
  __shared__ __align__(16) float ck[400];
  __shared__ float kva[180];
  __shared__ float mlds[81];
  __shared__ float avs[12], bvs[12];

  const int tid = threadIdx.x;
  const int bx = blockIdx.x, by = blockIdx.y, bz = blockIdx.z;
  const bool isRow = (by < 3);
  const int segi = isRow ? by : by - 3;
  const int fixedo = (segi == 2) ? 255 : segi;
  const int chC = bz & 7;
  const int rv = rp[bz], cv = cp[bz];
  const int ri = rv >> 1, rf = rv & 1, ci = cv >> 1, cf = cv & 1;

  if (tid < 12) {
    float av = rf ? DEC12c[tid] : (tid == 6 ? 1.f : 0.f);
    if (isRow) {
      const int xi = (2 + 4 * fixedo - ri) - 6 + tid;
      if (xi < 0 || xi >= HH) av = 0.f;
    }
    avs[tid] = av;
  } else if (tid < 24) {
    const int q = tid - 12;
    float bv = cf ? DEC12c[q] : (q == 6 ? 1.f : 0.f);
    if (!isRow) {
      const int xj = (2 + 4 * fixedo - ci) - 6 + q;
      if (xj < 0 || xj >= HH) bv = 0.f;
    }
    bvs[q] = bv;
  } else if (tid < 105) {
    const int m = tid - 24; mlds[m] = mtfp[m * 8 + chC];
  }
  __syncthreads();

  for (int i = tid; i < 180; i += 128) {
    const int S = i / 9, v = i - S * 9;
    const int plo = (S - 8 > 0) ? S - 8 : 0, phi = (S < 11) ? S : 11;
    float s1 = 0.f;
    for (int p = plo; p <= phi; ++p) s1 += avs[p] * mlds[(S - p) * 9 + v];
    kva[i] = s1;
  }
  __syncthreads();
  for (int i = tid; i < 400; i += 128) {
    const int S = i / 20, T = i - S * 20;
    const int qlo = (T - 8 > 0) ? T - 8 : 0, qhi = (T < 11) ? T : 11;
    float s1 = 0.f;
    for (int q = qlo; q <= qhi; ++q) s1 += bvs[q] * kva[S * 9 + (T - q)];
    ck[i] = s1;
  }

  const float* src = inp + ((size_t)bz << 20);
  if (isRow) {
    const int R0 = (2 + 4 * fixedo - ri) - 10;
    const int C0c = 512 * bx - 8 - ci;
    for (int i = tid; i < 20 * ECHUNK; i += 128) {
      const int rr = i / ECHUNK, jc = i - rr * ECHUNK;
      const float* grow = src + (clampi(R0 + rr) << 10);
      const int c0 = C0c + 4 * jc;
      float4 v;
      v.x = grow[clampi(c0 + 0)];
      v.y = grow[clampi(c0 + 1)];
      v.z = grow[clampi(c0 + 2)];
      v.w = grow[clampi(c0 + 3)];
      *(float4*)(tile + rr * ESPAN + 4 * jc) = v;
    }
  } else {
    const int Cw0 = (2 + 4 * fixedo - ci) - 10;
    const int Rr0 = 512 * bx - 8 - ri;
    for (int i = tid; i < 20 * ESPAN; i += 128) {
      const int T = i / ESPAN, rr = i - T * ESPAN;
      tile[T * ESPAN + rr] = src[(clampi(Rr0 + rr) << 10) + clampi(Cw0 + T)];
    }
  }
  __syncthreads();

  float acc = 0.f;
  #pragma unroll 4
  for (int L = 0; L < 20; ++L) {
    const float* wp = tile + L * ESPAN + 4 * tid;
    float w[20];
    #pragma unroll
    for (int j = 0; j < 5; ++j) {
      const float4 v = *(const float4*)(wp + 4 * j);
      w[4 * j] = v.x; w[4 * j + 1] = v.y; w[4 * j + 2] = v.z; w[4 * j + 3] = v.w;
    }
    if (isRow) {
      #pragma unroll
      for (int e = 0; e < 20; ++e) acc += ck[L * 20 + e] * w[e];
    } else {
      #pragma unroll
      for (int e = 0; e < 20; ++e) acc += ck[e * 20 + L] * w[e];
    }
  }

  int oi, oj;
  if (isRow) { oi = fixedo; oj = 128 * bx + tid; }
  else       { oj = fixedo; oi = 128 * bx + tid; }
  outg[((size_t)bz * OHW + oi) * OHW + oj] = acc;
}

// ---------------- corner fixup ----------------
__global__ __launch_bounds__(64) void dgp_cornerfix(
    const float* __restrict__ inp, const float* __restrict__ mtfp,
    const int* __restrict__ rp, const int* __restrict__ cp,
    float* __restrict__ outg) {
  __shared__ float mlds[81];
  __shared__ float avs[12], bvs[12];
  const int lane = threadIdx.x;
  const int bi = blockIdx.x, bj = blockIdx.y, bz = blockIdx.z;
  const int oi = (bi == 2) ? 255 : bi;
  const int oj = (bj == 2) ? 255 : bj;
  const int chC = bz & 7;
  const int rv = rp[bz], cv = cp[bz];
  const int ri = rv >> 1, rf = rv & 1, ci = cv >> 1, cf = cv & 1;

  if (lane < 12)       avs[lane] = rf ? DEC12c[lane] : (lane == 6 ? 1.f : 0.f);
  else if (lane < 24)  bvs[lane - 12] = cf ? DEC12c[lane - 12] : (lane - 12 == 6 ? 1.f : 0.f);
  for (int m = lane; m < 81; m += 64) mlds[m] = mtfp[m * 8 + chC];
  __syncthreads();

  const int Ri = 2 + 4 * oi - ri;
  const int Cj = 2 + 4 * oj - ci;
  const float* src = inp + ((size_t)bz << 20);

  float acc = 0.f;
  for (int pair = lane; pair < 144; pair += 64) {
    const int p = pair / 12, q = pair - 12 * (pair / 12);
    const int xi = Ri - 6 + p, xj = Cj - 6 + q;
    if (xi < 0 || xi >= HH || xj < 0 || xj >= HH) continue;
    const float ab = avs[p] * bvs[q];
    if (ab == 0.f) continue;
    float s = 0.f;
    #pragma unroll
    for (int u = 0; u < 9; ++u) {
      const float* grow = src + (clampi(xi - 4 + u) << 10);
      #pragma unroll
      for (int v = 0; v < 9; ++v) s += mlds[u * 9 + v] * grow[clampi(xj - 4 + v)];
    }
    acc += ab * s;
  }
  #pragma unroll
  for (int off = 32; off > 0; off >>= 1) acc += __shfl_down(acc, off);
  if (lane == 0) outg[((size_t)bz * OHW + oi) * OHW + oj] = acc;
}

extern "C" void kernel_launch(void* const* d_in, const int* in_sizes, int n_in,
                              void* d_out, int out_size, void* d_ws, size_t ws_size,
                              hipStream_t stream) {
  const float* inp  = (const float*)d_in[0];
  const float* mtfp = (const float*)d_in[1];
  const int*   rp   = (const int*)d_in[2];
  const int*   cp   = (const int*)d_in[3];
  float* outg = (float*)d_out;
  hipLaunchKernelGGL(dgp_main, dim3(OHW / TW, OHW / TH, 32), dim3(NTHREADS), 0, stream,
                     inp, mtfp, rp, cp, outg);
  hipLaunchKernelGGL(dgp_edgefix, dim3(2, 6, 32), dim3(128), 0, stream,
                     inp, mtfp, rp, cp, outg);
  hipLaunchKernelGGL(dgp_cornerfix, dim3(3, 3, 32), dim3(64), 0, stream,
                     inp, mtfp, rp, cp, outg);
}